// Round 3
// baseline (1062.143 us; speedup 1.0000x reference)
//
#include <hip/hip_runtime.h>

constexpr int PIX   = 513 * 513;  // 263169
constexpr int NIN   = 64;
constexpr int NOUT  = 64;
constexpr int PPB   = 64;         // pixels per block (one wave-width)
constexpr int OPG   = 16;         // outputs per wave-group (64 / 4 waves)

// S = over + under, D = over - under
// A_o = sum_i W[o,i]*S[i],  B_o = sum_i |W[o,i]|*D[i]
// out_over  = 0.5*(A + B) + bias = 0.5*((A + 2b) + B)
// out_under = 0.5*(A - B) + bias = 0.5*((A + 2b) - B)
__global__ __launch_bounds__(256, 6) void combined_bounds_kernel(
    const float* __restrict__ under,
    const float* __restrict__ over,
    const float* __restrict__ W,
    const float* __restrict__ bias,
    float* __restrict__ out_under,
    float* __restrict__ out_over)
{
    __shared__ float Wl[NOUT * NIN];  // natural layout [o][i], 16 KB
    __shared__ float Bl[NOUT];

    // Stage weights: consecutive lanes -> consecutive addresses, conflict-free
    {
        const int t = threadIdx.x;
        #pragma unroll
        for (int k = 0; k < 16; ++k)
            Wl[t + 256 * k] = W[t + 256 * k];
        if (t < NOUT) Bl[t] = bias[t];
    }
    __syncthreads();

    const int lane = threadIdx.x & 63;   // pixel within block slice
    const int g    = threadIdx.x >> 6;   // output group = wave id
    const int p    = blockIdx.x * PPB + lane;
    if (p >= PIX) return;
    const int o0 = g * OPG;

    const float* op = over  + p;
    const float* up = under + p;

    // 32 accumulators/thread; bias pre-folded as A' = A + 2b
    float accA[OPG], accB[OPG];
    #pragma unroll
    for (int j = 0; j < OPG; ++j) {
        accA[j] = 2.0f * Bl[o0 + j];
        accB[j] = 0.0f;
    }

    #pragma unroll 4
    for (int i = 0; i < NIN; i += 4) {
        float S[4], D[4];
        #pragma unroll
        for (int q = 0; q < 4; ++q) {
            const float ov = op[(size_t)(i + q) * PIX];
            const float uv = up[(size_t)(i + q) * PIX];
            S[q] = ov + uv;
            D[q] = ov - uv;
        }
        #pragma unroll
        for (int j = 0; j < OPG; ++j) {
            // wave-uniform broadcast read, 16B aligned
            const float4 w4 = *(const float4*)&Wl[(o0 + j) * NIN + i];
            accA[j] += w4.x * S[0];  accB[j] += fabsf(w4.x) * D[0];
            accA[j] += w4.y * S[1];  accB[j] += fabsf(w4.y) * D[1];
            accA[j] += w4.z * S[2];  accB[j] += fabsf(w4.z) * D[2];
            accA[j] += w4.w * S[3];  accB[j] += fabsf(w4.w) * D[3];
        }
    }

    #pragma unroll
    for (int j = 0; j < OPG; ++j) {
        const int o = o0 + j;
        const float vo = 0.5f * (accA[j] + accB[j]);
        const float vu = 0.5f * (accA[j] - accB[j]);
        __builtin_nontemporal_store(vo, &out_over[(size_t)o * PIX + p]);
        __builtin_nontemporal_store(vu, &out_under[(size_t)o * PIX + p]);
    }
}

extern "C" void kernel_launch(void* const* d_in, const int* in_sizes, int n_in,
                              void* d_out, int out_size, void* d_ws, size_t ws_size,
                              hipStream_t stream) {
    const float* under = (const float*)d_in[0];
    const float* over  = (const float*)d_in[1];
    const float* W     = (const float*)d_in[2];
    const float* bias  = (const float*)d_in[3];
    float* out_under = (float*)d_out;
    float* out_over  = out_under + (size_t)NOUT * PIX;

    const int blocks = (PIX + PPB - 1) / PPB;  // 4113
    combined_bounds_kernel<<<blocks, 256, 0, stream>>>(under, over, W, bias,
                                                       out_under, out_over);
}

// Round 4
// 121.341 us; speedup vs baseline: 8.7534x; 8.7534x over previous
//
#include <hip/hip_runtime.h>

constexpr int PIX  = 513 * 513;  // 263169
constexpr int NIN  = 64;
constexpr int NOUT = 64;
constexpr int PPB  = 64;         // pixels per block (one wave width)

// S = over + under, D = over - under
// A_o = sum_i W[o,i]*S[i],  B_o = sum_i |W[o,i]|*D[i]
// out_over  = 0.5*(A + 2b + B) ; out_under = 0.5*(A + 2b - B)
__global__ __launch_bounds__(256, 4) void combined_bounds_kernel(
    const float* __restrict__ under,
    const float* __restrict__ over,
    const float* __restrict__ W,
    const float* __restrict__ bias,
    float* __restrict__ out_under,
    float* __restrict__ out_over)
{
    __shared__ float Wl[NOUT * NIN];  // natural layout [o][i], 16 KB
    __shared__ float Bl[NOUT];

    // Conflict-free staging: consecutive lanes -> consecutive addresses
    {
        const int t = threadIdx.x;
        #pragma unroll
        for (int k = 0; k < 16; ++k)
            Wl[t + 256 * k] = W[t + 256 * k];
        if (t < NOUT) Bl[t] = bias[t];
    }
    __syncthreads();

    const int lane = threadIdx.x & 63;
    const int g    = threadIdx.x >> 6;     // wave id -> output group
    const int p    = blockIdx.x * PPB + lane;
    if (p >= PIX) return;                  // no barriers after this point
    const int o0 = g * 16;

    const float* op = over  + p;
    const float* up = under + p;

    // 32 named scalar accumulators — cannot be demoted to scratch.
#define DECL_ACC(j) float aA##j = 2.0f * Bl[o0 + j], aB##j = 0.0f;
    DECL_ACC(0)  DECL_ACC(1)  DECL_ACC(2)  DECL_ACC(3)
    DECL_ACC(4)  DECL_ACC(5)  DECL_ACC(6)  DECL_ACC(7)
    DECL_ACC(8)  DECL_ACC(9)  DECL_ACC(10) DECL_ACC(11)
    DECL_ACC(12) DECL_ACC(13) DECL_ACC(14) DECL_ACC(15)
#undef DECL_ACC

    #pragma unroll 2
    for (int i = 0; i < NIN; i += 4) {
        const float ov0 = op[(size_t)(i + 0) * PIX], uv0 = up[(size_t)(i + 0) * PIX];
        const float ov1 = op[(size_t)(i + 1) * PIX], uv1 = up[(size_t)(i + 1) * PIX];
        const float ov2 = op[(size_t)(i + 2) * PIX], uv2 = up[(size_t)(i + 2) * PIX];
        const float ov3 = op[(size_t)(i + 3) * PIX], uv3 = up[(size_t)(i + 3) * PIX];
        const float S0 = ov0 + uv0, D0 = ov0 - uv0;
        const float S1 = ov1 + uv1, D1 = ov1 - uv1;
        const float S2 = ov2 + uv2, D2 = ov2 - uv2;
        const float S3 = ov3 + uv3, D3 = ov3 - uv3;

        // Wave-uniform broadcast ds_read_b128 per output row
#define DO_J(j) { const float4 w = *(const float4*)&Wl[(o0 + j) * NIN + i];      \
        aA##j += w.x * S0;  aB##j += fabsf(w.x) * D0;                            \
        aA##j += w.y * S1;  aB##j += fabsf(w.y) * D1;                            \
        aA##j += w.z * S2;  aB##j += fabsf(w.z) * D2;                            \
        aA##j += w.w * S3;  aB##j += fabsf(w.w) * D3; }
        DO_J(0)  DO_J(1)  DO_J(2)  DO_J(3)
        DO_J(4)  DO_J(5)  DO_J(6)  DO_J(7)
        DO_J(8)  DO_J(9)  DO_J(10) DO_J(11)
        DO_J(12) DO_J(13) DO_J(14) DO_J(15)
#undef DO_J
    }

#define STORE_J(j) {                                                             \
        const float vo = 0.5f * (aA##j + aB##j);                                 \
        const float vu = 0.5f * (aA##j - aB##j);                                 \
        __builtin_nontemporal_store(vo, &out_over [(size_t)(o0 + j) * PIX + p]); \
        __builtin_nontemporal_store(vu, &out_under[(size_t)(o0 + j) * PIX + p]); }
    STORE_J(0)  STORE_J(1)  STORE_J(2)  STORE_J(3)
    STORE_J(4)  STORE_J(5)  STORE_J(6)  STORE_J(7)
    STORE_J(8)  STORE_J(9)  STORE_J(10) STORE_J(11)
    STORE_J(12) STORE_J(13) STORE_J(14) STORE_J(15)
#undef STORE_J
}

extern "C" void kernel_launch(void* const* d_in, const int* in_sizes, int n_in,
                              void* d_out, int out_size, void* d_ws, size_t ws_size,
                              hipStream_t stream) {
    const float* under = (const float*)d_in[0];
    const float* over  = (const float*)d_in[1];
    const float* W     = (const float*)d_in[2];
    const float* bias  = (const float*)d_in[3];
    float* out_under = (float*)d_out;
    float* out_over  = out_under + (size_t)NOUT * PIX;

    const int blocks = (PIX + PPB - 1) / PPB;  // 4113
    combined_bounds_kernel<<<blocks, 256, 0, stream>>>(under, over, W, bias,
                                                       out_under, out_over);
}

// Round 5
// 116.869 us; speedup vs baseline: 9.0883x; 1.0383x over previous
//
#include <hip/hip_runtime.h>

constexpr int PIX  = 513 * 513;  // 263169 = 2056*128 + 1
constexpr int NIN  = 64;
constexpr int NOUT = 64;
constexpr int PPB  = 128;        // pixels per block (64 lanes x 2 px/thread)

// S = over + under, D = over - under
// A_o = sum_i W[o,i]*S[i],  B_o = sum_i |W[o,i]|*D[i]
// out_over  = 0.5*(A + 2b + B) ; out_under = 0.5*(A + 2b - B)
__global__ __launch_bounds__(256, 4) void combined_bounds_kernel(
    const float* __restrict__ under,
    const float* __restrict__ over,
    const float* __restrict__ W,
    const float* __restrict__ bias,
    float* __restrict__ out_under,
    float* __restrict__ out_over)
{
    __shared__ float Wl[NOUT * NIN];  // natural [o][i], 16 KB
    __shared__ float Bl[NOUT];

    {
        const int t = threadIdx.x;
        #pragma unroll
        for (int k = 0; k < 16; ++k)
            Wl[t + 256 * k] = W[t + 256 * k];
        if (t < NOUT) Bl[t] = bias[t];
    }
    __syncthreads();

    const int lane = threadIdx.x & 63;
    const int g    = threadIdx.x >> 6;      // wave id -> output group
    const int o0   = g * 16;

    const int pixbase = blockIdx.x * PPB;

    if (pixbase + PPB <= PIX) {
        // ---------- fast path: all 128 pixels valid ----------
        const int p0 = pixbase + lane;       // pixel A
        const int p1 = p0 + 64;              // pixel B
        const float* oa = over  + p0;
        const float* ua = under + p0;
        const float* ob = over  + p1;
        const float* ub = under + p1;

        // 64 named scalar accumulators (2 px x 16 outputs x {A,B})
#define DECL_ACC(j) const float tb##j = 2.0f * Bl[o0 + j];                  \
        float aAa##j = tb##j, aBa##j = 0.f, aAb##j = tb##j, aBb##j = 0.f;
        DECL_ACC(0)  DECL_ACC(1)  DECL_ACC(2)  DECL_ACC(3)
        DECL_ACC(4)  DECL_ACC(5)  DECL_ACC(6)  DECL_ACC(7)
        DECL_ACC(8)  DECL_ACC(9)  DECL_ACC(10) DECL_ACC(11)
        DECL_ACC(12) DECL_ACC(13) DECL_ACC(14) DECL_ACC(15)
#undef DECL_ACC

        #pragma unroll 2
        for (int i = 0; i < NIN; i += 4) {
            float Sa0,Da0,Sa1,Da1,Sa2,Da2,Sa3,Da3;
            float Sb0,Db0,Sb1,Db1,Sb2,Db2,Sb3,Db3;
            {
                const float oa0 = oa[(size_t)(i+0)*PIX], ua0 = ua[(size_t)(i+0)*PIX];
                const float oa1 = oa[(size_t)(i+1)*PIX], ua1 = ua[(size_t)(i+1)*PIX];
                const float oa2 = oa[(size_t)(i+2)*PIX], ua2 = ua[(size_t)(i+2)*PIX];
                const float oa3 = oa[(size_t)(i+3)*PIX], ua3 = ua[(size_t)(i+3)*PIX];
                const float ob0 = ob[(size_t)(i+0)*PIX], ub0 = ub[(size_t)(i+0)*PIX];
                const float ob1 = ob[(size_t)(i+1)*PIX], ub1 = ub[(size_t)(i+1)*PIX];
                const float ob2 = ob[(size_t)(i+2)*PIX], ub2 = ub[(size_t)(i+2)*PIX];
                const float ob3 = ob[(size_t)(i+3)*PIX], ub3 = ub[(size_t)(i+3)*PIX];
                Sa0 = oa0+ua0; Da0 = oa0-ua0;  Sa1 = oa1+ua1; Da1 = oa1-ua1;
                Sa2 = oa2+ua2; Da2 = oa2-ua2;  Sa3 = oa3+ua3; Da3 = oa3-ua3;
                Sb0 = ob0+ub0; Db0 = ob0-ub0;  Sb1 = ob1+ub1; Db1 = ob1-ub1;
                Sb2 = ob2+ub2; Db2 = ob2-ub2;  Sb3 = ob3+ub3; Db3 = ob3-ub3;
            }
            // one broadcast ds_read_b128 feeds 16 FMAs
#define DO_J(j) { const float4 w = *(const float4*)&Wl[(o0 + j) * NIN + i];  \
            aAa##j += w.x*Sa0;  aBa##j += fabsf(w.x)*Da0;                    \
            aAb##j += w.x*Sb0;  aBb##j += fabsf(w.x)*Db0;                    \
            aAa##j += w.y*Sa1;  aBa##j += fabsf(w.y)*Da1;                    \
            aAb##j += w.y*Sb1;  aBb##j += fabsf(w.y)*Db1;                    \
            aAa##j += w.z*Sa2;  aBa##j += fabsf(w.z)*Da2;                    \
            aAb##j += w.z*Sb2;  aBb##j += fabsf(w.z)*Db2;                    \
            aAa##j += w.w*Sa3;  aBa##j += fabsf(w.w)*Da3;                    \
            aAb##j += w.w*Sb3;  aBb##j += fabsf(w.w)*Db3; }
            DO_J(0)  DO_J(1)  DO_J(2)  DO_J(3)
            DO_J(4)  DO_J(5)  DO_J(6)  DO_J(7)
            DO_J(8)  DO_J(9)  DO_J(10) DO_J(11)
            DO_J(12) DO_J(13) DO_J(14) DO_J(15)
#undef DO_J
        }

#define STORE_J(j) {                                                          \
        const size_t rb = (size_t)(o0 + j) * PIX;                             \
        __builtin_nontemporal_store(0.5f*(aAa##j + aBa##j), &out_over [rb + p0]); \
        __builtin_nontemporal_store(0.5f*(aAa##j - aBa##j), &out_under[rb + p0]); \
        __builtin_nontemporal_store(0.5f*(aAb##j + aBb##j), &out_over [rb + p1]); \
        __builtin_nontemporal_store(0.5f*(aAb##j - aBb##j), &out_under[rb + p1]); }
        STORE_J(0)  STORE_J(1)  STORE_J(2)  STORE_J(3)
        STORE_J(4)  STORE_J(5)  STORE_J(6)  STORE_J(7)
        STORE_J(8)  STORE_J(9)  STORE_J(10) STORE_J(11)
        STORE_J(12) STORE_J(13) STORE_J(14) STORE_J(15)
#undef STORE_J
    } else {
        // ---------- tail path: last block, few valid pixels ----------
        for (int t = lane; pixbase + t < PIX; t += 64) {
            const int p = pixbase + t;
            #pragma unroll 1
            for (int j = 0; j < 16; ++j) {
                const int o = o0 + j;
                float A = 2.0f * Bl[o], B = 0.f;
                for (int i = 0; i < NIN; ++i) {
                    const float ov = over[(size_t)i * PIX + p];
                    const float uv = under[(size_t)i * PIX + p];
                    const float w  = Wl[o * NIN + i];
                    A += w * (ov + uv);
                    B += fabsf(w) * (ov - uv);
                }
                out_over [(size_t)o * PIX + p] = 0.5f * (A + B);
                out_under[(size_t)o * PIX + p] = 0.5f * (A - B);
            }
        }
    }
}

extern "C" void kernel_launch(void* const* d_in, const int* in_sizes, int n_in,
                              void* d_out, int out_size, void* d_ws, size_t ws_size,
                              hipStream_t stream) {
    const float* under = (const float*)d_in[0];
    const float* over  = (const float*)d_in[1];
    const float* W     = (const float*)d_in[2];
    const float* bias  = (const float*)d_in[3];
    float* out_under = (float*)d_out;
    float* out_over  = out_under + (size_t)NOUT * PIX;

    const int blocks = (PIX + PPB - 1) / PPB;  // 2057
    combined_bounds_kernel<<<blocks, 256, 0, stream>>>(under, over, W, bias,
                                                       out_under, out_over);
}

// Round 6
// 71.941 us; speedup vs baseline: 14.7641x; 1.6245x over previous
//
#include <hip/hip_runtime.h>

constexpr int PIX   = 513 * 513;  // 263169 = 2056*128 + 1
constexpr int NTILE = 128;        // pixels per block

typedef short bf16x8 __attribute__((ext_vector_type(8)));
typedef float f32x4  __attribute__((ext_vector_type(4)));

// RNE f32 -> bf16 bits
__device__ __forceinline__ unsigned short f2bf(float f) {
    unsigned u = __builtin_bit_cast(unsigned, f);
    u += 0x7fffu + ((u >> 16) & 1u);
    return (unsigned short)(u >> 16);
}

// C[128 x P] = Wbig[128 x 128] * X[128 x P] + bias
//   X rows 0..63 = inputs_over, rows 64..127 = inputs_under
//   Wbig = [[w+, w-], [w-, w+]] ; C rows 0..63 -> out_over, 64..127 -> out_under
__global__ __launch_bounds__(256, 2) void mfma_bounds_kernel(
    const float* __restrict__ under,
    const float* __restrict__ over,
    const float* __restrict__ W,
    const float* __restrict__ bias,
    float* __restrict__ out_under,
    float* __restrict__ out_over)
{
    __shared__ alignas(16) unsigned short Wl[128 * 128];  // bf16, swizzled rows
    __shared__ alignas(16) unsigned short Xt[NTILE * 128];// bf16, [px][k], swizzled
    __shared__ float Bl[64];

    const int t = threadIdx.x;
    const int pxbase = blockIdx.x * NTILE;

    if (pxbase + NTILE > PIX) {
        // ---- tail block: remaining pixels, scalar f32 path ----
        if (t < 128) {
            const int m = t;
            const int o = m & 63;
            const float* prim = (m < 64) ? over  : under;
            const float* sec  = (m < 64) ? under : over;
            for (int p = pxbase; p < PIX; ++p) {
                float acc = bias[o];
                for (int i = 0; i < 64; ++i) {
                    const float w = W[o * 64 + i];
                    acc += fmaxf(w, 0.f) * prim[(size_t)i * PIX + p]
                         + fminf(w, 0.f) * sec [(size_t)i * PIX + p];
                }
                if (m < 64) out_over [(size_t)m        * PIX + p] = acc;
                else        out_under[(size_t)(m - 64) * PIX + p] = acc;
            }
        }
        return;
    }

    // ---- stage Wbig into LDS as bf16 (swizzle: byte ^= (row&7)<<4) ----
    #pragma unroll 4
    for (int e = 0; e < 32; ++e) {
        const int pidx = t + 256 * e;        // 0..8191 -> (row, col-pair)
        const int r  = pidx >> 6;            // 0..127
        const int c0 = (pidx & 63) * 2;      // even col; pair never straddles 64
        const float w0 = W[(r & 63) * 64 + (c0 & 63)];
        const float w1 = W[(r & 63) * 64 + ((c0 + 1) & 63)];
        const bool same = ((c0 < 64) == (r < 64));
        const float v0 = same ? fmaxf(w0, 0.f) : fminf(w0, 0.f);
        const float v1 = same ? fmaxf(w1, 0.f) : fminf(w1, 0.f);
        const unsigned pack = (unsigned)f2bf(v0) | ((unsigned)f2bf(v1) << 16);
        const int off = r * 256 + ((c0 * 2) ^ ((r & 7) << 4));
        *(unsigned*)((char*)Wl + off) = pack;
    }
    if (t < 64) Bl[t] = bias[t];

    // ---- stage X tile transposed: Xt[px][k] bf16, swizzled ----
    {
        const int px    = t & 127;
        const int khalf = t >> 7;                 // 0: k 0..63 (over), 1: 64..127 (under)
        const float* src = khalf ? under : over;
        const size_t p = (size_t)pxbase + px;
        #pragma unroll 8
        for (int j = 0; j < 32; ++j) {
            const int row = 2 * j;                // row, row+1 within src
            const float x0 = src[(size_t)row       * PIX + p];
            const float x1 = src[(size_t)(row + 1) * PIX + p];
            const unsigned pack = (unsigned)f2bf(x0) | ((unsigned)f2bf(x1) << 16);
            const int kbyte = 4 * j + 128 * khalf;   // = k0*2
            const int off = px * 256 + (kbyte ^ ((px & 7) << 4));
            *(unsigned*)((char*)Xt + off) = pack;
        }
    }
    __syncthreads();

    // ---- MFMA compute: wave w owns C rows [32w, 32w+32) ----
    const int wv   = t >> 6;
    const int lane = t & 63;
    const int lrow = lane & 15;    // fragment row/col index
    const int lg   = lane >> 4;    // fragment k-group / C row-group
    const int m0   = wv * 32;

    // bias per accumulator register (C row = m0 + mt*16 + lg*4 + r)
    float bf[2][4];
    #pragma unroll
    for (int mt = 0; mt < 2; ++mt)
        #pragma unroll
        for (int r = 0; r < 4; ++r)
            bf[mt][r] = Bl[(m0 + mt * 16 + lg * 4 + r) & 63];

    // A fragments: A[row = m0+mt*16+lrow][k = ks*32 + lg*8 + e]
    bf16x8 A[2][4];
    #pragma unroll
    for (int mt = 0; mt < 2; ++mt)
        #pragma unroll
        for (int ks = 0; ks < 4; ++ks) {
            const int row = m0 + mt * 16 + lrow;
            const int ch  = ks * 4 + lg;          // 16B chunk index along k
            A[mt][ks] = *(const bf16x8*)((const char*)Wl +
                          row * 256 + ((ch * 16) ^ ((row & 7) << 4)));
        }

    f32x4 acc[2][8];
    #pragma unroll
    for (int mt = 0; mt < 2; ++mt)
        #pragma unroll
        for (int nt = 0; nt < 8; ++nt) {
            f32x4 v = {bf[mt][0], bf[mt][1], bf[mt][2], bf[mt][3]};
            acc[mt][nt] = v;
        }

    #pragma unroll
    for (int nt = 0; nt < 8; ++nt) {
        bf16x8 Bf[4];
        #pragma unroll
        for (int ks = 0; ks < 4; ++ks) {
            const int prow = nt * 16 + lrow;      // pixel row in Xt
            const int ch   = ks * 4 + lg;
            Bf[ks] = *(const bf16x8*)((const char*)Xt +
                       prow * 256 + ((ch * 16) ^ ((prow & 7) << 4)));
        }
        #pragma unroll
        for (int mt = 0; mt < 2; ++mt)
            #pragma unroll
            for (int ks = 0; ks < 4; ++ks)
                acc[mt][nt] = __builtin_amdgcn_mfma_f32_16x16x32_bf16(
                    A[mt][ks], Bf[ks], acc[mt][nt], 0, 0, 0);
    }

    // ---- store: C[m][p], col = lane&15, row = lg*4 + r (verified layout) ----
    #pragma unroll
    for (int mt = 0; mt < 2; ++mt)
        #pragma unroll
        for (int r = 0; r < 4; ++r) {
            const int m = m0 + mt * 16 + lg * 4 + r;
            float* base = (m < 64) ? (out_over  + (size_t)m        * PIX)
                                   : (out_under + (size_t)(m - 64) * PIX);
            #pragma unroll
            for (int nt = 0; nt < 8; ++nt)
                __builtin_nontemporal_store(acc[mt][nt][r],
                    base + pxbase + nt * 16 + lrow);
        }
}

extern "C" void kernel_launch(void* const* d_in, const int* in_sizes, int n_in,
                              void* d_out, int out_size, void* d_ws, size_t ws_size,
                              hipStream_t stream) {
    const float* under = (const float*)d_in[0];
    const float* over  = (const float*)d_in[1];
    const float* W     = (const float*)d_in[2];
    const float* bias  = (const float*)d_in[3];
    float* out_under = (float*)d_out;
    float* out_over  = out_under + (size_t)64 * PIX;

    const int blocks = (PIX + NTILE - 1) / NTILE;  // 2057
    mfma_bounds_kernel<<<blocks, 256, 0, stream>>>(under, over, W, bias,
                                                   out_under, out_over);
}